// Round 13
// baseline (284.804 us; speedup 1.0000x reference)
//
#include <hip/hip_runtime.h>
#include <stdint.h>

#define NJ 316  // L*P + Lx = 16 + 300

typedef __attribute__((ext_vector_type(8))) short short8;
typedef __attribute__((ext_vector_type(4))) float f32x4;
union U4S8 { uint4 u; short8 s; };

__device__ __forceinline__ unsigned short f2bf(float x) {
    unsigned int u = __float_as_uint(x);
    u += 0x7fff + ((u >> 16) & 1);
    return (unsigned short)(u >> 16);
}
__device__ __forceinline__ float bf2f(unsigned short h) {
    return __uint_as_float(((unsigned int)h) << 16);
}

// ---------------------------------------------------------------------------
// cvt_all: fused conversions, ZERO LDS (R11 lesson: per-kernel LDS kills the
// memory-bound branch's occupancy). New segment: wj[9][256] head-mix softmax.
// ---------------------------------------------------------------------------
__global__ __launch_bounds__(256) void cvt_all_kernel(
    const float* __restrict__ q,  unsigned short* __restrict__ qh,  unsigned short* __restrict__ ql,
    const float* __restrict__ ak, unsigned short* __restrict__ akh, unsigned short* __restrict__ akl,
    const float* __restrict__ wv, unsigned short* __restrict__ wvh, unsigned short* __restrict__ wvl,
    const float* __restrict__ inflat, unsigned int* __restrict__ inflatP,
    const float* __restrict__ Wattn, unsigned short* __restrict__ wah, unsigned short* __restrict__ wal,
    unsigned short* __restrict__ v2th, unsigned short* __restrict__ v2tl,
    const float* __restrict__ Wmix, float* __restrict__ wjbuf)
{
    int i = blockIdx.x * 256 + threadIdx.x;        // 0 .. 893951
    if (i < 760576) {
        const float* s; unsigned short *dh, *dl; int off; bool pack = false;
        unsigned int* dp = nullptr;
        if (i < 131072)      { s = q;  dh = qh;  dl = ql;  off = i; }
        else if (i < 150272) { s = ak; dh = akh; dl = akl; off = i - 131072; }
        else if (i < 412416) { s = wv; dh = wvh; dl = wvl; off = i - 150272; }
        else { s = inflat; dp = inflatP; off = i - 412416; pack = true; dh = dl = nullptr; }
        float4 v = ((const float4*)s)[off];
        float x[4] = {v.x, v.y, v.z, v.w};
        unsigned short h[4], l[4];
        #pragma unroll
        for (int j = 0; j < 4; ++j) {
            h[j] = f2bf(x[j]);
            l[j] = f2bf(x[j] - bf2f(h[j]));
        }
        if (pack) {
            ((uint4*)dp)[off] = make_uint4(
                (unsigned)h[0] | ((unsigned)l[0] << 16),
                (unsigned)h[1] | ((unsigned)l[1] << 16),
                (unsigned)h[2] | ((unsigned)l[2] << 16),
                (unsigned)h[3] | ((unsigned)l[3] << 16));
        } else {
            ((uint2*)dh)[off] = make_uint2((unsigned)h[0] | ((unsigned)h[1] << 16),
                                           (unsigned)h[2] | ((unsigned)h[3] << 16));
            ((uint2*)dl)[off] = make_uint2((unsigned)l[0] | ((unsigned)l[1] << 16),
                                           (unsigned)l[2] | ((unsigned)l[3] << 16));
        }
    } else if (i < 891648) {
        int off = i - 760576;                      // float4 units over [8][65536]
        int base = off * 4;
        int z = base >> 16, r = base & 65535;
        float4 v = *(const float4*)&Wattn[(size_t)(4 * z + 4) * 65536 + r];
        float x[4] = {v.x, v.y, v.z, v.w};
        unsigned short h[4], l[4];
        #pragma unroll
        for (int j = 0; j < 4; ++j) {
            h[j] = f2bf(x[j]);
            l[j] = f2bf(x[j] - bf2f(h[j]));
        }
        ((uint2*)wah)[off] = make_uint2((unsigned)h[0] | ((unsigned)h[1] << 16),
                                        (unsigned)h[2] | ((unsigned)h[3] << 16));
        ((uint2*)wal)[off] = make_uint2((unsigned)l[0] | ((unsigned)l[1] << 16),
                                        (unsigned)l[2] | ((unsigned)l[3] << 16));
    } else if (i < 893696) {
        int j = i - 891648;                        // 0..2047: one V2T row each
        size_t base = (size_t)j * 320;
        uint2 zz = make_uint2(0u, 0u);
        #pragma unroll
        for (int d = 0; d < 4; ++d) {              // k 0..15
            ((uint2*)(v2th + base))[d] = zz;
            ((uint2*)(v2tl + base))[d] = zz;
        }
        ((uint2*)(v2th + base + 316))[0] = zz;     // k 316..319
        ((uint2*)(v2tl + base + 316))[0] = zz;
    } else {
        int c = i - 893696;                        // 0..255: head-mix softmax
        if (c < 256) {
            float wv9[9], m = -1e30f;
            #pragma unroll
            for (int j = 0; j < 9; ++j) {
                wv9[j] = Wmix[c * 9 + j];
                m = fmaxf(m, wv9[j]);
            }
            float s = 0.f;
            #pragma unroll
            for (int j = 0; j < 9; ++j) { wv9[j] = expf(wv9[j] - m); s += wv9[j]; }
            float inv = 1.f / s;
            #pragma unroll
            for (int j = 0; j < 9; ++j) wjbuf[j * 256 + c] = wv9[j] * inv;
        }
    }
}

// ---------------------------------------------------------------------------
// Split-bf16 MFMA GEMM core. BM=64 BN=128 BK=32, 4 waves. smem = 30720 B.
// Seg.nprod: 1 = ah*bh, 2 = +al*bh (A full, B hi), 3 = +ah*bl (full split).
// ---------------------------------------------------------------------------
struct Seg {
    const unsigned short *Ah, *Al, *Bh, *Bl;
    int K, lda, ldb;
    long sA, sB;
    int nprod;
};

template<int NSEG>
__device__ __forceinline__ void gemm_mainloop(
    const Seg& s0, const Seg& s1, int M, int N, int nb, int mb, int z,
    char* smem, f32x4 (&acc)[2][4])
{
    unsigned short* As0 = (unsigned short*)smem;            // [2][2560]
    unsigned short* Bs0 = (unsigned short*)(smem + 10240);  // [2][5120]
    const int t = threadIdx.x;
    const int lane = t & 63;
    const int wave = t >> 6;
    const int wm = (wave & 1) * 32, wn = (wave >> 1) * 64;

    const int arow = t >> 2, akoff = (t & 3) * 8;
    const int frow = lane & 15, fk = (lane >> 4) * 8;

    #pragma unroll
    for (int seg = 0; seg < NSEG; ++seg) {
        const Seg S = seg ? s1 : s0;
        const int np = S.nprod;
        const unsigned short* Azh = S.Ah + (size_t)z * S.sA;
        const unsigned short* Azl = (np >= 2) ? S.Al + (size_t)z * S.sA : nullptr;
        const unsigned short* Bzh = S.Bh + (size_t)z * S.sB;
        const unsigned short* Bzl = (np >= 3) ? S.Bl + (size_t)z * S.sB : nullptr;
        for (int kb = 0; kb < S.K; kb += 32) {
            __syncthreads();
            {
                int gm = mb + arow;
                uint4 vh = {0, 0, 0, 0}, vl = {0, 0, 0, 0};
                if (gm < M) {
                    size_t o = (size_t)gm * S.lda + kb + akoff;
                    vh = *(const uint4*)(Azh + o);
                    if (np >= 2) vl = *(const uint4*)(Azl + o);
                }
                *(uint4*)&As0[arow * 40 + akoff] = vh;
                if (np >= 2) *(uint4*)&As0[2560 + arow * 40 + akoff] = vl;
                #pragma unroll
                for (int i = 0; i < 2; ++i) {
                    int f = i * 256 + t;
                    int brow = f >> 2, bkoff = (f & 3) * 8;
                    int gn = nb + brow;
                    uint4 wh = {0, 0, 0, 0}, wl = {0, 0, 0, 0};
                    if (gn < N) {
                        size_t o = (size_t)gn * S.ldb + kb + bkoff;
                        wh = *(const uint4*)(Bzh + o);
                        if (np >= 3) wl = *(const uint4*)(Bzl + o);
                    }
                    *(uint4*)&Bs0[brow * 40 + bkoff] = wh;
                    if (np >= 3) *(uint4*)&Bs0[5120 + brow * 40 + bkoff] = wl;
                }
            }
            __syncthreads();
            short8 a[2][2], b[4][2];
            #pragma unroll
            for (int i = 0; i < 2; ++i) {
                int r = wm + i * 16 + frow;
                a[i][0] = *(const short8*)&As0[r * 40 + fk];
                if (np >= 2) a[i][1] = *(const short8*)&As0[2560 + r * 40 + fk];
            }
            #pragma unroll
            for (int j = 0; j < 4; ++j) {
                int r = wn + j * 16 + frow;
                b[j][0] = *(const short8*)&Bs0[r * 40 + fk];
                if (np >= 3) b[j][1] = *(const short8*)&Bs0[5120 + r * 40 + fk];
            }
            #pragma unroll
            for (int i = 0; i < 2; ++i)
                #pragma unroll
                for (int j = 0; j < 4; ++j) {
                    acc[i][j] = __builtin_amdgcn_mfma_f32_16x16x32_bf16(
                        a[i][0], b[j][0], acc[i][j], 0, 0, 0);
                    if (np >= 2)
                        acc[i][j] = __builtin_amdgcn_mfma_f32_16x16x32_bf16(
                            a[i][1], b[j][0], acc[i][j], 0, 0, 0);
                    if (np >= 3)
                        acc[i][j] = __builtin_amdgcn_mfma_f32_16x16x32_bf16(
                            a[i][0], b[j][1], acc[i][j], 0, 0, 0);
                }
        }
    }
}

template<bool ACCUM, bool OUTF32, int NSEG>
__device__ __forceinline__ void gemm_core(
    const Seg& s0, const Seg& s1,
    float* __restrict__ Cf, unsigned short* __restrict__ Ch,
    unsigned short* __restrict__ Cl,
    int M, int N, int ldc, long sC, int nb, int mb, int z, char* smem)
{
    const int lane = threadIdx.x & 63;
    const int wave = threadIdx.x >> 6;
    const int wm = (wave & 1) * 32, wn = (wave >> 1) * 64;
    f32x4 acc[2][4];
    #pragma unroll
    for (int i = 0; i < 2; ++i)
        #pragma unroll
        for (int j = 0; j < 4; ++j) acc[i][j] = (f32x4){0.f, 0.f, 0.f, 0.f};
    gemm_mainloop<NSEG>(s0, s1, M, N, nb, mb, z, smem, acc);
    #pragma unroll
    for (int i = 0; i < 2; ++i)
        #pragma unroll
        for (int r = 0; r < 4; ++r) {
            int gm = mb + wm + i * 16 + (lane >> 4) * 4 + r;
            if (gm >= M) continue;
            #pragma unroll
            for (int j = 0; j < 4; ++j) {
                int gn = nb + wn + j * 16 + (lane & 15);
                if (gn >= N) continue;
                size_t idx = (size_t)z * sC + (size_t)gm * ldc + gn;
                float v = acc[i][j][r];
                if (OUTF32) {
                    float prev = ACCUM ? Cf[idx] : 0.f;
                    Cf[idx] = prev + v;
                } else {
                    unsigned short h = f2bf(v);
                    Ch[idx] = h;
                    Cl[idx] = f2bf(v - bf2f(h));
                }
            }
        }
}

template<bool ACCUM, bool OUTF32, int NSEG>
__global__ __launch_bounds__(256) void mfma_gemm(
    Seg s0, Seg s1,
    float* __restrict__ Cf, unsigned short* __restrict__ Ch,
    unsigned short* __restrict__ Cl,
    int M, int N, int ldc, long sC)
{
    __shared__ __align__(16) char smem[30720];
    gemm_core<ACCUM, OUTF32, NSEG>(s0, s1, Cf, Ch, Cl, M, N, ldc, sC,
                                   blockIdx.x * 128, blockIdx.y * 64,
                                   blockIdx.z, smem);
}

// ---------------------------------------------------------------------------
// oh_out: OH GEMM with FUSED head-mix epilogue. Per block (z, 64 q-rows,
// 128 c-cols): acc = KA@Wv0^T (2-prod) + aw@V2T^T (1-prod); then
// atomicAdd(out, wj[z,c]*(acc + s0*bv0 + (1-s0)*bv1) [+ qf*wj8 if z==0]).
// out zeroed via hipMemsetAsync; 8 fp32 commutative adds per element.
// ---------------------------------------------------------------------------
__global__ __launch_bounds__(256) void oh_out_kernel(
    Seg a, Seg b, const float* __restrict__ qf, const float* __restrict__ s0,
    const float* __restrict__ bv, const float* __restrict__ wj,
    float* __restrict__ out)
{
    __shared__ __align__(16) char smem[30720];
    const int nb = blockIdx.x * 128, mb = blockIdx.y * 64;
    const int z = blockIdx.z;
    const int lane = threadIdx.x & 63;
    const int wave = threadIdx.x >> 6;
    const int wm = (wave & 1) * 32, wn = (wave >> 1) * 64;

    f32x4 acc[2][4];
    #pragma unroll
    for (int i = 0; i < 2; ++i)
        #pragma unroll
        for (int j = 0; j < 4; ++j) acc[i][j] = (f32x4){0.f, 0.f, 0.f, 0.f};
    gemm_mainloop<2>(a, b, 2048, 256, nb, mb, z, smem, acc);

    #pragma unroll
    for (int j = 0; j < 4; ++j) {
        int gn = nb + wn + j * 16 + (lane & 15);
        float bv0g = bv[(2 * z) * 256 + gn];
        float bv1g = bv[(2 * z + 1) * 256 + gn];
        float wjz  = wj[z * 256 + gn];
        float wj8  = wj[8 * 256 + gn];
        #pragma unroll
        for (int i = 0; i < 2; ++i)
            #pragma unroll
            for (int r = 0; r < 4; ++r) {
                int gm = mb + wm + i * 16 + (lane >> 4) * 4 + r;
                float s0v = s0[z * 2048 + gm];
                float val = (acc[i][j][r] + s0v * bv0g + (1.f - s0v) * bv1g)
                            * wjz;
                if (z == 0) val += qf[(size_t)gm * 256 + gn] * wj8;
                atomicAdd(&out[(size_t)gm * 256 + gn], val);
            }
    }
}

// ---------------------------------------------------------------------------
// dual_lin: Bh GEMM (bx 0-1) + V2T GEMM (bx 2-4) + lin (bx 5-11), grid
// (12,5,8). 480 blocks -> <=2/CU anyway, so the 58.4 KB union LDS is free.
// ---------------------------------------------------------------------------
__global__ __launch_bounds__(256) void dual_lin_kernel(
    Seg a, Seg b,
    unsigned short* __restrict__ Bhh, unsigned short* __restrict__ Bhl,
    unsigned short* __restrict__ V2Th, unsigned short* __restrict__ V2Tl,
    const float* __restrict__ q, const float* __restrict__ refp,
    const int* __restrict__ iss, const int* __restrict__ lsi,
    const float* __restrict__ Woff, const float* __restrict__ boff,
    int* __restrict__ lin)
{
    __shared__ __align__(16) char smem[58368];
    const int bx = blockIdx.x;
    if (bx < 2) {
        gemm_core<false, false, 1>(a, a, nullptr, Bhh, Bhl,
                                   300, 256, 256, 320L * 256,
                                   bx * 128, blockIdx.y * 64, blockIdx.z, smem);
        return;
    }
    if (bx < 5) {
        if ((int)blockIdx.y * 64 >= 256) return;
        gemm_core<false, false, 1>(b, b, nullptr, V2Th, V2Tl,
                                   256, 300, 320, 256L * 320,
                                   (bx - 2) * 128, blockIdx.y * 64, blockIdx.z,
                                   smem);
        return;
    }
    const int idx = (bx - 5) * 40 + blockIdx.y * 8 + blockIdx.z;
    if (idx >= 256) return;

    // ---- lin job (R1-verified math, BK=32) ----
    float (*qf8)[256]  = (float(*)[256])smem;             //  8192 B
    float (*wtile)[33] = (float(*)[33])(smem + 8192);     // 33792 B
    double (*offl)[256]= (double(*)[256])(smem + 41984);  // 16384 B
    const int t = threadIdx.x;
    const int qbase = idx * 8;
    #pragma unroll
    for (int i = 0; i < 8; ++i) qf8[i][t] = q[(qbase + i) * 256 + t];
    double acc[8];
    #pragma unroll
    for (int r = 0; r < 8; ++r) acc[r] = 0.0;
    for (int cb = 0; cb < 256; cb += 32) {
        __syncthreads();
        #pragma unroll
        for (int i = 0; i < 32; ++i) {
            int f = i * 256 + t;
            int o = f >> 5, jj = f & 31;
            wtile[o][jj] = Woff[o * 256 + cb + jj];
        }
        __syncthreads();
        #pragma unroll
        for (int jj = 0; jj < 32; ++jj) {
            double wvv = (double)wtile[t][jj];
            #pragma unroll
            for (int r = 0; r < 8; ++r)
                acc[r] += (double)qf8[r][cb + jj] * wvv;
        }
    }
    double bo = (double)boff[t];
    __syncthreads();
    #pragma unroll
    for (int r = 0; r < 8; ++r) offl[r][t] = acc[r] + bo;
    __syncthreads();
    #pragma unroll
    for (int rep = 0; rep < 4; ++rep) {
        int id2 = rep * 256 + t;
        int r = id2 >> 7;
        int s = id2 & 127;
        int l = (s >> 2) & 3;
        int qq = qbase + r;
        double offx = offl[r][2 * s];
        double offy = offl[r][2 * s + 1];
        int w0 = iss[l * 2 + 0];
        int w1 = iss[l * 2 + 1];
        double locx = (double)refp[qq * 8 + l * 2 + 0] + offx / (double)w1;
        double locy = (double)refp[qq * 8 + l * 2 + 1] + offy / (double)w0;
        locx = fmin(fmax(locx, 0.0), 0.999);
        locy = fmin(fmax(locy, 0.0), 0.999);
        int ix = (int)(locx * (double)w0);
        int iy = (int)(locy * (double)w1);
        lin[qq * 128 + s] = ix + iy * w0 + lsi[l];
    }
}

// ---------------------------------------------------------------------------
// gattn_attnA: gattn (bx<1024, R3/R9 empirical-optimum structure) + attn_a
// logits GEMM (bx>=1024, 768 blocks) sharing one dispatch / 69.6 KB LDS.
// ---------------------------------------------------------------------------
__global__ __launch_bounds__(256, 2) void gattn_attnA(
    const unsigned short* __restrict__ qh, const unsigned short* __restrict__ ql,
    const unsigned int* __restrict__ inflatP, const float* __restrict__ Wattn,
    const int* __restrict__ lin, float* __restrict__ attn, Seg aA)
{
    __shared__ __align__(16) char smem[69632];
    const int t = threadIdx.x;

    if ((int)blockIdx.x >= 1024) {
        int idx = blockIdx.x - 1024;               // 0..767
        int z = idx & 7, my = (idx >> 3) & 31, nx = idx >> 8;  // nx 0..2
        gemm_core<false, true, 1>(aA, aA, attn + 16, nullptr, nullptr,
                                  2048, 300, NJ, 2048L * NJ,
                                  nx * 128, my * 64, z, smem);
        return;
    }

    int* linrow = (int*)smem;                      // [256]
    float (*Glds)[268] = (float(*)[268])(smem + 1024);  // [64][268]
    const int lane = t & 63, w = t >> 6;
    const int b = blockIdx.x;
    const int qb = b & 7, p = (b >> 3) & 3, l = (b >> 5) & 3, h = b >> 7;
    linrow[t] = lin[(256 * qb + t) * 128 + h * 16 + l * 4 + p];
    __syncthreads();

    const int l15 = lane & 15, g = lane >> 4;
    const int q2l = qb + 8 * p + 32 * l15;         // q2 for i=0; +512 per i
    const int ebase = 64 * w + l15;

    f32x4 acc[4][4];
    #pragma unroll
    for (int i = 0; i < 4; ++i)
        #pragma unroll
        for (int eg = 0; eg < 4; ++eg) acc[i][eg] = (f32x4){0.f, 0.f, 0.f, 0.f};

    for (int kb = 0; kb < 256; kb += 32) {
        U4S8 ah[4], al[4];
        #pragma unroll
        for (int i = 0; i < 4; ++i) {
            size_t off = (size_t)(q2l + 512 * i) * 256 + kb + 8 * g;
            ah[i].u = *(const uint4*)(qh + off);
            al[i].u = *(const uint4*)(ql + off);
        }
        int rowoff[8];
        #pragma unroll
        for (int m = 0; m < 8; ++m) rowoff[m] = linrow[kb + 8 * g + m] * 256;
        unsigned int uv[4][8];
        #pragma unroll
        for (int eg = 0; eg < 4; ++eg)
            #pragma unroll
            for (int m = 0; m < 8; ++m)
                uv[eg][m] = inflatP[rowoff[m] + ebase + 16 * eg];

        #pragma unroll
        for (int eg = 0; eg < 4; ++eg) {
            U4S8 bh, bl;
            unsigned int hh[4], ll[4];
            #pragma unroll
            for (int d = 0; d < 4; ++d) {
                hh[d] = __builtin_amdgcn_perm(uv[eg][2 * d + 1], uv[eg][2 * d],
                                              0x05040100u);
                ll[d] = __builtin_amdgcn_perm(uv[eg][2 * d + 1], uv[eg][2 * d],
                                              0x07060302u);
            }
            bh.u = make_uint4(hh[0], hh[1], hh[2], hh[3]);
            bl.u = make_uint4(ll[0], ll[1], ll[2], ll[3]);
            #pragma unroll
            for (int i = 0; i < 4; ++i) {
                acc[i][eg] = __builtin_amdgcn_mfma_f32_16x16x32_bf16(
                    ah[i].s, bh.s, acc[i][eg], 0, 0, 0);
                acc[i][eg] = __builtin_amdgcn_mfma_f32_16x16x32_bf16(
                    ah[i].s, bl.s, acc[i][eg], 0, 0, 0);
                acc[i][eg] = __builtin_amdgcn_mfma_f32_16x16x32_bf16(
                    al[i].s, bh.s, acc[i][eg], 0, 0, 0);
            }
        }
    }

    // dump G (C-layout: row = 16i+4g+r, col = 64w+16eg+l15) to LDS
    #pragma unroll
    for (int i = 0; i < 4; ++i)
        #pragma unroll
        for (int eg = 0; eg < 4; ++eg)
            #pragma unroll
            for (int r = 0; r < 4; ++r)
                Glds[16 * i + 4 * g + r][64 * w + 16 * eg + l15] = acc[i][eg][r];
    __syncthreads();

    // fp32 epilogue: contract G rows with Ws rows, shuffle-reduce over tx
    const int tx = t & 15, ty = t >> 4;
    const float* Wsbase = Wattn + (size_t)(h * 4 + l) * 65536;
    float gv[4][16];
    #pragma unroll
    for (int r = 0; r < 4; ++r)
        #pragma unroll
        for (int i2 = 0; i2 < 4; ++i2) {
            float4 gd = *(const float4*)&Glds[ty * 4 + r][tx * 4 + 64 * i2];
            gv[r][i2 * 4 + 0] = gd.x;
            gv[r][i2 * 4 + 1] = gd.y;
            gv[r][i2 * 4 + 2] = gd.z;
            gv[r][i2 * 4 + 3] = gd.w;
        }
    #pragma unroll
    for (int r = 0; r < 4; ++r) {
        int hi = ty * 4 + r;
        int q2 = qb + 8 * p + 32 * hi;
        #pragma unroll
        for (int p2 = 0; p2 < 4; ++p2) {
            const float* wr = Wsbase + (size_t)(hi + 64 * p2) * 256;
            float partial = 0.f;
            #pragma unroll
            for (int i2 = 0; i2 < 4; ++i2) {
                float4 wv = *(const float4*)&wr[tx * 4 + 64 * i2];
                partial += wv.x * gv[r][i2 * 4 + 0] + wv.y * gv[r][i2 * 4 + 1]
                         + wv.z * gv[r][i2 * 4 + 2] + wv.w * gv[r][i2 * 4 + 3];
            }
            partial += __shfl_xor(partial, 1);
            partial += __shfl_xor(partial, 2);
            partial += __shfl_xor(partial, 4);
            partial += __shfl_xor(partial, 8);
            if (tx == 0)
                attn[((size_t)h * 2048 + q2) * NJ + (l * 4 + p2)] = partial;
        }
    }
}

// ---------------------------------------------------------------------------
// Fused softmax (316 logits) + ka gather: one block per (h,q).
// ---------------------------------------------------------------------------
__global__ __launch_bounds__(256) void softmax_ka_kernel(
    const float* __restrict__ attn, const unsigned int* __restrict__ inflatP,
    const int* __restrict__ lin, float* __restrict__ s0,
    unsigned short* __restrict__ awh,
    unsigned short* __restrict__ KAh, unsigned short* __restrict__ KAl)
{
    __shared__ float red[8];
    __shared__ float w16[16];
    __shared__ int lls[16];
    const int t = threadIdx.x;
    const int lane = t & 63, w = t >> 6;
    const int rid = blockIdx.x;              // h*2048 + q
    const int h = rid >> 11, q = rid & 2047;
    const float* row = attn + (size_t)rid * NJ;

    float v0 = row[t];
    float v1 = (t < 60) ? row[256 + t] : -1e30f;
    float m = fmaxf(v0, v1);
    #pragma unroll
    for (int d = 1; d < 64; d <<= 1) m = fmaxf(m, __shfl_xor(m, d));
    if (lane == 0) red[w] = m;
    __syncthreads();
    m = fmaxf(fmaxf(red[0], red[1]), fmaxf(red[2], red[3]));

    float e0 = expf(v0 - m);
    float e1 = (t < 60) ? expf(v1 - m) : 0.f;
    float s = e0 + e1;
    #pragma unroll
    for (int d = 1; d < 64; d <<= 1) s += __shfl_xor(s, d);
    if (lane == 0) red[4 + w] = s;
    __syncthreads();
    s = (red[4] + red[5]) + (red[6] + red[7]);
    const float inv = 1.f / s;

    float sf = (t < 16) ? e0 : 0.f;
    #pragma unroll
    for (int d = 1; d < 64; d <<= 1) sf += __shfl_xor(sf, d);
    if (lane == 0) red[w] = sf;

    float a0 = e0 * inv;
    float a1 = (t < 60) ? e1 * inv : 0.f;
    awh[(size_t)rid * 320 + t] = f2bf(a0);
    if (t < 64)
        awh[(size_t)rid * 320 + 256 + t] = f2bf(a1);
    if (t < 16) {
        w16[t] = a0;
        lls[t] = lin[q * 128 + h * 16 + t];
    }
    __syncthreads();
    if (t == 0)
        s0[rid] = ((red[0] + red[1]) + (red[2] + red[3])) * inv;

    float acc = 0.f;
    #pragma unroll
    for (int k = 0; k < 16; ++k) {
        unsigned int u = inflatP[lls[k] * 256 + t];
        acc += w16[k] * (bf2f((unsigned short)(u & 0xffff)) +
                         bf2f((unsigned short)(u >> 16)));
    }
    unsigned short hh = f2bf(acc);
    KAh[(size_t)rid * 256 + t] = hh;
    KAl[(size_t)rid * 256 + t] = f2bf(acc - bf2f(hh));
}

// ---------------------------------------------------------------------------
extern "C" void kernel_launch(void* const* d_in, const int* in_sizes, int n_in,
                              void* d_out, int out_size, void* d_ws, size_t ws_size,
                              hipStream_t stream) {
    const float* query = (const float*)d_in[0];
    const float* refp  = (const float*)d_in[1];
    const float* inflat= (const float*)d_in[2];
    const int*   iss   = (const int*)d_in[3];
    const float* ak    = (const float*)d_in[4];
    const int*   lsi   = (const int*)d_in[5];
    const float* Woff  = (const float*)d_in[6];
    const float* boff  = (const float*)d_in[7];
    const float* Wattn = (const float*)d_in[8];
    const float* Wv    = (const float*)d_in[9];
    const float* bv    = (const float*)d_in[10];
    const float* Wmix  = (const float*)d_in[11];
    float* out = (float*)d_out;

    typedef unsigned short us;
    char* ws = (char*)d_ws;
    int* lin    = (int*)ws;   ws += (size_t)262144 * 4;
    float* attn = (float*)ws; ws += (size_t)8 * 2048 * NJ * 4;
    float* s0   = (float*)ws; ws += (size_t)8 * 2048 * 4;
    float* wjbuf= (float*)ws; ws += (size_t)9 * 256 * 4;
    unsigned int* inflatP = (unsigned int*)ws; ws += (size_t)1392640 * 4;
    us* qh  = (us*)ws; ws += (size_t)524288 * 2;
    us* ql  = (us*)ws; ws += (size_t)524288 * 2;
    us* akh = (us*)ws; ws += (size_t)320 * 256 * 2;
    us* akl = (us*)ws; ws += (size_t)320 * 256 * 2;
    us* Waddh = (us*)ws; ws += (size_t)524288 * 2;
    us* Waddl = (us*)ws; ws += (size_t)524288 * 2;
    us* Wvh = (us*)ws; ws += (size_t)1048576 * 2;
    us* Wvl = (us*)ws; ws += (size_t)1048576 * 2;
    us* Bhh = (us*)ws; ws += (size_t)8 * 320 * 256 * 2;
    us* Bhl = (us*)ws; ws += (size_t)8 * 320 * 256 * 2;
    us* V2Th= (us*)ws; ws += (size_t)8 * 256 * 320 * 2;   // [z][c][k], k-pad 0
    us* V2Tl= (us*)ws; ws += (size_t)8 * 256 * 320 * 2;
    us* awh = (us*)ws; ws += (size_t)8 * 2048 * 320 * 2;
    us* KAh = (us*)ws; ws += (size_t)8 * 2048 * 256 * 2;
    us* KAl = (us*)ws; ws += (size_t)8 * 2048 * 256 * 2;

    // zero the output accumulator (stream-ordered; capture-safe)
    hipMemsetAsync(out, 0, (size_t)out_size * 4, stream);

    cvt_all_kernel<<<3492, 256, 0, stream>>>(
        query, qh, ql, ak, akh, akl, Wv, Wvh, Wvl,
        inflat, inflatP, Wattn, Waddh, Waddl, V2Th, V2Tl, Wmix, wjbuf);

    // Bh gemm + V2T gemm + lin, one dispatch (480 blocks)
    {
        Seg a = {akh, akl, Waddh, Waddl, 256, 256, 256, 0L, 65536L, 3};
        Seg b = {Wvh + 65536, Wvl + 65536, akh, nullptr, 256, 256, 256,
                 131072L, 0L, 2};
        dual_lin_kernel<<<dim3(12, 5, 8), 256, 0, stream>>>(
            a, b, Bhh, Bhl, V2Th + 16, V2Tl + 16,
            query, refp, iss, lsi, Woff, boff, lin);
    }

    // gattn (1024 blocks) + attn_a logits GEMM (768 blocks), one dispatch
    {
        Seg aA = {qh, ql, Bhh, Bhl, 256, 256, 256, 0L, 320L * 256, 3};
        gattn_attnA<<<1792, 256, 0, stream>>>(qh, ql, inflatP, Wattn, lin,
                                              attn, aA);
    }

    softmax_ka_kernel<<<16384, 256, 0, stream>>>(attn, inflatP, lin, s0,
                                                 awh, KAh, KAl);

    // out += wj*(KA@Wv0^T + aw@V2T^T + bias) [+ qf*wj8]  (fused OH+final)
    {
        Seg a = {KAh, KAl, Wvh, nullptr, 256, 256, 256, 2048L * 256,
                 2L * 65536, 2};
        Seg b = {awh, nullptr, V2Th, nullptr, 320, 320, 320, 2048L * 320,
                 256L * 320, 1};
        oh_out_kernel<<<dim3(2, 32, 8), 256, 0, stream>>>(
            a, b, query, s0, bv, wjbuf, out);
    }
}

// Round 14
// 268.055 us; speedup vs baseline: 1.0625x; 1.0625x over previous
//
#include <hip/hip_runtime.h>
#include <stdint.h>

#define NJ 316  // L*P + Lx = 16 + 300

typedef __attribute__((ext_vector_type(8))) short short8;
typedef __attribute__((ext_vector_type(4))) float f32x4;
union U4S8 { uint4 u; short8 s; };

__device__ __forceinline__ unsigned short f2bf(float x) {
    unsigned int u = __float_as_uint(x);
    u += 0x7fff + ((u >> 16) & 1);
    return (unsigned short)(u >> 16);
}
__device__ __forceinline__ float bf2f(unsigned short h) {
    return __uint_as_float(((unsigned int)h) << 16);
}

// ---------------------------------------------------------------------------
// One fused conversion kernel (6 segments, float4-granular):
//   S0 query->hi/lo  S1 ak->hi/lo  S2 Wv->hi/lo  S3 inflat->packed
//   S4 Wadd slices->hi/lo  S5 V2T pad zeroing
// ---------------------------------------------------------------------------
__global__ __launch_bounds__(256) void cvt_all_kernel(
    const float* __restrict__ q,  unsigned short* __restrict__ qh,  unsigned short* __restrict__ ql,
    const float* __restrict__ ak, unsigned short* __restrict__ akh, unsigned short* __restrict__ akl,
    const float* __restrict__ wv, unsigned short* __restrict__ wvh, unsigned short* __restrict__ wvl,
    const float* __restrict__ inflat, unsigned int* __restrict__ inflatP,
    const float* __restrict__ Wattn, unsigned short* __restrict__ wah, unsigned short* __restrict__ wal,
    unsigned short* __restrict__ v2th, unsigned short* __restrict__ v2tl)
{
    int i = blockIdx.x * 256 + threadIdx.x;        // 0 .. 893695
    if (i < 760576) {
        const float* s; unsigned short *dh, *dl; int off; bool pack = false;
        unsigned int* dp = nullptr;
        if (i < 131072)      { s = q;  dh = qh;  dl = ql;  off = i; }
        else if (i < 150272) { s = ak; dh = akh; dl = akl; off = i - 131072; }
        else if (i < 412416) { s = wv; dh = wvh; dl = wvl; off = i - 150272; }
        else { s = inflat; dp = inflatP; off = i - 412416; pack = true; dh = dl = nullptr; }
        float4 v = ((const float4*)s)[off];
        float x[4] = {v.x, v.y, v.z, v.w};
        unsigned short h[4], l[4];
        #pragma unroll
        for (int j = 0; j < 4; ++j) {
            h[j] = f2bf(x[j]);
            l[j] = f2bf(x[j] - bf2f(h[j]));
        }
        if (pack) {
            ((uint4*)dp)[off] = make_uint4(
                (unsigned)h[0] | ((unsigned)l[0] << 16),
                (unsigned)h[1] | ((unsigned)l[1] << 16),
                (unsigned)h[2] | ((unsigned)l[2] << 16),
                (unsigned)h[3] | ((unsigned)l[3] << 16));
        } else {
            ((uint2*)dh)[off] = make_uint2((unsigned)h[0] | ((unsigned)h[1] << 16),
                                           (unsigned)h[2] | ((unsigned)h[3] << 16));
            ((uint2*)dl)[off] = make_uint2((unsigned)l[0] | ((unsigned)l[1] << 16),
                                           (unsigned)l[2] | ((unsigned)l[3] << 16));
        }
    } else if (i < 891648) {
        int off = i - 760576;                      // float4 units over [8][65536]
        int base = off * 4;
        int z = base >> 16, r = base & 65535;
        float4 v = *(const float4*)&Wattn[(size_t)(4 * z + 4) * 65536 + r];
        float x[4] = {v.x, v.y, v.z, v.w};
        unsigned short h[4], l[4];
        #pragma unroll
        for (int j = 0; j < 4; ++j) {
            h[j] = f2bf(x[j]);
            l[j] = f2bf(x[j] - bf2f(h[j]));
        }
        ((uint2*)wah)[off] = make_uint2((unsigned)h[0] | ((unsigned)h[1] << 16),
                                        (unsigned)h[2] | ((unsigned)h[3] << 16));
        ((uint2*)wal)[off] = make_uint2((unsigned)l[0] | ((unsigned)l[1] << 16),
                                        (unsigned)l[2] | ((unsigned)l[3] << 16));
    } else {
        int j = i - 891648;                        // 0..2047: one V2T row each
        size_t base = (size_t)j * 320;             // [z*256+r][320]
        uint2 zz = make_uint2(0u, 0u);
        #pragma unroll
        for (int d = 0; d < 4; ++d) {              // k 0..15
            ((uint2*)(v2th + base))[d] = zz;
            ((uint2*)(v2tl + base))[d] = zz;
        }
        ((uint2*)(v2th + base + 316))[0] = zz;     // k 316..319
        ((uint2*)(v2tl + base + 316))[0] = zz;
    }
}

// ---------------------------------------------------------------------------
// lin_kernel: fp64 offsets -> sampling indices (verified R1)
// ---------------------------------------------------------------------------
__global__ __launch_bounds__(256) void lin_kernel(
    const float* __restrict__ query, const float* __restrict__ refp,
    const int* __restrict__ iss, const int* __restrict__ lsi,
    const float* __restrict__ Woff, const float* __restrict__ boff,
    int* __restrict__ lin)
{
    __shared__ float qf8[8][256];
    __shared__ float wtile[256][33];
    __shared__ double offl[8][256];
    const int t = threadIdx.x;
    const int qbase = blockIdx.x * 8;
    #pragma unroll
    for (int i = 0; i < 8; ++i) qf8[i][t] = query[(qbase + i) * 256 + t];
    double acc[8];
    #pragma unroll
    for (int r = 0; r < 8; ++r) acc[r] = 0.0;
    for (int cb = 0; cb < 256; cb += 32) {
        __syncthreads();
        #pragma unroll
        for (int i = 0; i < 32; ++i) {
            int f = i * 256 + t;
            int o = f >> 5, jj = f & 31;
            wtile[o][jj] = Woff[o * 256 + cb + jj];
        }
        __syncthreads();
        #pragma unroll
        for (int jj = 0; jj < 32; ++jj) {
            double wv = (double)wtile[t][jj];
            #pragma unroll
            for (int r = 0; r < 8; ++r)
                acc[r] += (double)qf8[r][cb + jj] * wv;
        }
    }
    double bo = (double)boff[t];
    __syncthreads();
    #pragma unroll
    for (int r = 0; r < 8; ++r) offl[r][t] = acc[r] + bo;
    __syncthreads();
    #pragma unroll
    for (int rep = 0; rep < 4; ++rep) {
        int idx = rep * 256 + t;
        int r = idx >> 7;
        int s = idx & 127;
        int l = (s >> 2) & 3;
        int q = qbase + r;
        double offx = offl[r][2 * s];
        double offy = offl[r][2 * s + 1];
        int w0 = iss[l * 2 + 0];
        int w1 = iss[l * 2 + 1];
        double locx = (double)refp[q * 8 + l * 2 + 0] + offx / (double)w1;
        double locy = (double)refp[q * 8 + l * 2 + 1] + offy / (double)w0;
        locx = fmin(fmax(locx, 0.0), 0.999);
        locy = fmin(fmax(locy, 0.0), 0.999);
        int ix = (int)(locx * (double)w0);
        int iy = (int)(locy * (double)w1);
        lin[q * 128 + s] = ix + iy * w0 + lsi[l];
    }
}

// ---------------------------------------------------------------------------
// gattn_mfma: EXACT R3 variant — empirically fastest (65-70 us measured).
// Register law established R4-R10: acc[4][4]+gather needs ~156 regs; every
// forced-occupancy variant ((256,{3,4,5}), LDS staging, e-split, manual SW
// pipeline) lost to spill / ILP loss / doubled A-traffic. 2 blocks/CU is
// optimal for this structure. Direct L2 gathers; fp32 epilogue; plain stores.
// ---------------------------------------------------------------------------
__global__ __launch_bounds__(256, 2) void gattn_mfma(
    const unsigned short* __restrict__ qh, const unsigned short* __restrict__ ql,
    const unsigned int* __restrict__ inflatP, const float* __restrict__ Wattn,
    const int* __restrict__ lin, float* __restrict__ attn)
{
    __shared__ int linrow[256];
    __shared__ float Glds[64][268];
    const int t = threadIdx.x;
    const int lane = t & 63, w = t >> 6;
    const int b = blockIdx.x;
    const int qb = b & 7, p = (b >> 3) & 3, l = (b >> 5) & 3, h = b >> 7;
    linrow[t] = lin[(256 * qb + t) * 128 + h * 16 + l * 4 + p];
    __syncthreads();

    const int l15 = lane & 15, g = lane >> 4;
    const int q2l = qb + 8 * p + 32 * l15;      // q2 for i=0; +512 per i
    const int ebase = 64 * w + l15;

    f32x4 acc[4][4];
    #pragma unroll
    for (int i = 0; i < 4; ++i)
        #pragma unroll
        for (int eg = 0; eg < 4; ++eg) acc[i][eg] = (f32x4){0.f, 0.f, 0.f, 0.f};

    for (int kb = 0; kb < 256; kb += 32) {
        U4S8 ah[4], al[4];
        #pragma unroll
        for (int i = 0; i < 4; ++i) {
            size_t off = (size_t)(q2l + 512 * i) * 256 + kb + 8 * g;
            ah[i].u = *(const uint4*)(qh + off);
            al[i].u = *(const uint4*)(ql + off);
        }
        int rowoff[8];
        #pragma unroll
        for (int m = 0; m < 8; ++m) rowoff[m] = linrow[kb + 8 * g + m] * 256;
        unsigned int uv[4][8];
        #pragma unroll
        for (int eg = 0; eg < 4; ++eg)
            #pragma unroll
            for (int m = 0; m < 8; ++m)
                uv[eg][m] = inflatP[rowoff[m] + ebase + 16 * eg];

        #pragma unroll
        for (int eg = 0; eg < 4; ++eg) {
            U4S8 bh, bl;
            unsigned int hh[4], ll[4];
            #pragma unroll
            for (int d = 0; d < 4; ++d) {
                hh[d] = __builtin_amdgcn_perm(uv[eg][2 * d + 1], uv[eg][2 * d],
                                              0x05040100u);
                ll[d] = __builtin_amdgcn_perm(uv[eg][2 * d + 1], uv[eg][2 * d],
                                              0x07060302u);
            }
            bh.u = make_uint4(hh[0], hh[1], hh[2], hh[3]);
            bl.u = make_uint4(ll[0], ll[1], ll[2], ll[3]);
            #pragma unroll
            for (int i = 0; i < 4; ++i) {
                acc[i][eg] = __builtin_amdgcn_mfma_f32_16x16x32_bf16(
                    ah[i].s, bh.s, acc[i][eg], 0, 0, 0);
                acc[i][eg] = __builtin_amdgcn_mfma_f32_16x16x32_bf16(
                    ah[i].s, bl.s, acc[i][eg], 0, 0, 0);
                acc[i][eg] = __builtin_amdgcn_mfma_f32_16x16x32_bf16(
                    al[i].s, bh.s, acc[i][eg], 0, 0, 0);
            }
        }
    }

    // dump G (C-layout: row = 16i+4g+r, col = 64w+16eg+l15) to LDS
    #pragma unroll
    for (int i = 0; i < 4; ++i)
        #pragma unroll
        for (int eg = 0; eg < 4; ++eg)
            #pragma unroll
            for (int r = 0; r < 4; ++r)
                Glds[16 * i + 4 * g + r][64 * w + 16 * eg + l15] = acc[i][eg][r];
    __syncthreads();

    // fp32 epilogue: contract G rows with Ws rows, shuffle-reduce over tx
    const int tx = t & 15, ty = t >> 4;
    const float* Wsbase = Wattn + (size_t)(h * 4 + l) * 65536;
    float gv[4][16];
    #pragma unroll
    for (int r = 0; r < 4; ++r)
        #pragma unroll
        for (int i2 = 0; i2 < 4; ++i2) {
            float4 gd = *(const float4*)&Glds[ty * 4 + r][tx * 4 + 64 * i2];
            gv[r][i2 * 4 + 0] = gd.x;
            gv[r][i2 * 4 + 1] = gd.y;
            gv[r][i2 * 4 + 2] = gd.z;
            gv[r][i2 * 4 + 3] = gd.w;
        }
    #pragma unroll
    for (int r = 0; r < 4; ++r) {
        int hi = ty * 4 + r;
        int q2 = qb + 8 * p + 32 * hi;
        #pragma unroll
        for (int p2 = 0; p2 < 4; ++p2) {
            const float* wr = Wsbase + (size_t)(hi + 64 * p2) * 256;
            float partial = 0.f;
            #pragma unroll
            for (int i2 = 0; i2 < 4; ++i2) {
                float4 wv = *(const float4*)&wr[tx * 4 + 64 * i2];
                partial += wv.x * gv[r][i2 * 4 + 0] + wv.y * gv[r][i2 * 4 + 1]
                         + wv.z * gv[r][i2 * 4 + 2] + wv.w * gv[r][i2 * 4 + 3];
            }
            partial += __shfl_xor(partial, 1);
            partial += __shfl_xor(partial, 2);
            partial += __shfl_xor(partial, 4);
            partial += __shfl_xor(partial, 8);
            if (tx == 0)
                attn[((size_t)h * 2048 + q2) * NJ + (l * 4 + p2)] = partial;
        }
    }
}

// ---------------------------------------------------------------------------
// Split-bf16 MFMA GEMM core. BM=64 BN=128 BK=32, 4 waves.
// Seg.nprod: 1 = ah*bh, 2 = +al*bh (A full, B hi), 3 = +ah*bl (full split).
// ---------------------------------------------------------------------------
struct Seg {
    const unsigned short *Ah, *Al, *Bh, *Bl;
    int K, lda, ldb;
    long sA, sB;
    int nprod;
};

template<bool ACCUM, bool OUTF32, int NSEG>
__device__ __forceinline__ void gemm_core(
    const Seg& s0, const Seg& s1,
    float* __restrict__ Cf, unsigned short* __restrict__ Ch,
    unsigned short* __restrict__ Cl,
    int M, int N, int ldc, long sC, int nb, int mb, int z)
{
    __shared__ unsigned short As[2][64 * 40];
    __shared__ unsigned short Bs[2][128 * 40];
    const int t = threadIdx.x;
    const int lane = t & 63;
    const int wave = t >> 6;
    const int wm = (wave & 1) * 32, wn = (wave >> 1) * 64;

    f32x4 acc[2][4];
    #pragma unroll
    for (int i = 0; i < 2; ++i)
        #pragma unroll
        for (int j = 0; j < 4; ++j) acc[i][j] = (f32x4){0.f, 0.f, 0.f, 0.f};

    const int arow = t >> 2, akoff = (t & 3) * 8;
    const int frow = lane & 15, fk = (lane >> 4) * 8;

    #pragma unroll
    for (int seg = 0; seg < NSEG; ++seg) {
        const Seg S = seg ? s1 : s0;
        const int np = S.nprod;
        const unsigned short* Azh = S.Ah + (size_t)z * S.sA;
        const unsigned short* Azl = (np >= 2) ? S.Al + (size_t)z * S.sA : nullptr;
        const unsigned short* Bzh = S.Bh + (size_t)z * S.sB;
        const unsigned short* Bzl = (np >= 3) ? S.Bl + (size_t)z * S.sB : nullptr;
        for (int kb = 0; kb < S.K; kb += 32) {
            __syncthreads();
            {
                int gm = mb + arow;
                uint4 vh = {0, 0, 0, 0}, vl = {0, 0, 0, 0};
                if (gm < M) {
                    size_t o = (size_t)gm * S.lda + kb + akoff;
                    vh = *(const uint4*)(Azh + o);
                    if (np >= 2) vl = *(const uint4*)(Azl + o);
                }
                *(uint4*)&As[0][arow * 40 + akoff] = vh;
                if (np >= 2) *(uint4*)&As[1][arow * 40 + akoff] = vl;
                #pragma unroll
                for (int i = 0; i < 2; ++i) {
                    int f = i * 256 + t;
                    int brow = f >> 2, bkoff = (f & 3) * 8;
                    int gn = nb + brow;
                    uint4 wh = {0, 0, 0, 0}, wl = {0, 0, 0, 0};
                    if (gn < N) {
                        size_t o = (size_t)gn * S.ldb + kb + bkoff;
                        wh = *(const uint4*)(Bzh + o);
                        if (np >= 3) wl = *(const uint4*)(Bzl + o);
                    }
                    *(uint4*)&Bs[0][brow * 40 + bkoff] = wh;
                    if (np >= 3) *(uint4*)&Bs[1][brow * 40 + bkoff] = wl;
                }
            }
            __syncthreads();
            short8 a[2][2], b[4][2];
            #pragma unroll
            for (int i = 0; i < 2; ++i) {
                int r = wm + i * 16 + frow;
                a[i][0] = *(const short8*)&As[0][r * 40 + fk];
                if (np >= 2) a[i][1] = *(const short8*)&As[1][r * 40 + fk];
            }
            #pragma unroll
            for (int j = 0; j < 4; ++j) {
                int r = wn + j * 16 + frow;
                b[j][0] = *(const short8*)&Bs[0][r * 40 + fk];
                if (np >= 3) b[j][1] = *(const short8*)&Bs[1][r * 40 + fk];
            }
            #pragma unroll
            for (int i = 0; i < 2; ++i)
                #pragma unroll
                for (int j = 0; j < 4; ++j) {
                    acc[i][j] = __builtin_amdgcn_mfma_f32_16x16x32_bf16(
                        a[i][0], b[j][0], acc[i][j], 0, 0, 0);
                    if (np >= 2)
                        acc[i][j] = __builtin_amdgcn_mfma_f32_16x16x32_bf16(
                            a[i][1], b[j][0], acc[i][j], 0, 0, 0);
                    if (np >= 3)
                        acc[i][j] = __builtin_amdgcn_mfma_f32_16x16x32_bf16(
                            a[i][0], b[j][1], acc[i][j], 0, 0, 0);
                }
        }
    }
    #pragma unroll
    for (int i = 0; i < 2; ++i)
        #pragma unroll
        for (int r = 0; r < 4; ++r) {
            int gm = mb + wm + i * 16 + (lane >> 4) * 4 + r;
            if (gm >= M) continue;
            #pragma unroll
            for (int j = 0; j < 4; ++j) {
                int gn = nb + wn + j * 16 + (lane & 15);
                if (gn >= N) continue;
                size_t idx = (size_t)z * sC + (size_t)gm * ldc + gn;
                float v = acc[i][j][r];
                if (OUTF32) {
                    float prev = ACCUM ? Cf[idx] : 0.f;
                    Cf[idx] = prev + v;
                } else {
                    unsigned short h = f2bf(v);
                    Ch[idx] = h;
                    Cl[idx] = f2bf(v - bf2f(h));
                }
            }
        }
}

template<bool ACCUM, bool OUTF32, int NSEG>
__global__ __launch_bounds__(256) void mfma_gemm(
    Seg s0, Seg s1,
    float* __restrict__ Cf, unsigned short* __restrict__ Ch,
    unsigned short* __restrict__ Cl,
    int M, int N, int ldc, long sC)
{
    gemm_core<ACCUM, OUTF32, NSEG>(s0, s1, Cf, Ch, Cl, M, N, ldc, sC,
                                   blockIdx.x * 128, blockIdx.y * 64,
                                   blockIdx.z);
}

// Dual-job wrapper: two independent bf16-out GEMMs in one dispatch.
__global__ __launch_bounds__(256) void mfma_gemm_dual(
    Seg a, int Ma, int Na, int ldca, long sCa,
    unsigned short* __restrict__ Cha, unsigned short* __restrict__ Cla,
    Seg b, int Mb, int Nb, int ldcb, long sCb,
    unsigned short* __restrict__ Chb, unsigned short* __restrict__ Clb,
    int ax)
{
    Seg dummy = a;
    if ((int)blockIdx.x < ax) {
        if ((int)blockIdx.y * 64 >= Ma) return;
        gemm_core<false, false, 1>(a, dummy, nullptr, Cha, Cla,
                                   Ma, Na, ldca, sCa,
                                   blockIdx.x * 128, blockIdx.y * 64,
                                   blockIdx.z);
    } else {
        if ((int)blockIdx.y * 64 >= Mb) return;
        gemm_core<false, false, 1>(b, dummy, nullptr, Chb, Clb,
                                   Mb, Nb, ldcb, sCb,
                                   (blockIdx.x - ax) * 128, blockIdx.y * 64,
                                   blockIdx.z);
    }
}

// ---------------------------------------------------------------------------
// Fused softmax (316 logits) + ka gather: one block per (h,q).
// ---------------------------------------------------------------------------
__global__ __launch_bounds__(256) void softmax_ka_kernel(
    const float* __restrict__ attn, const unsigned int* __restrict__ inflatP,
    const int* __restrict__ lin, float* __restrict__ s0,
    unsigned short* __restrict__ awh,
    unsigned short* __restrict__ KAh, unsigned short* __restrict__ KAl)
{
    __shared__ float red[8];
    __shared__ float w16[16];
    __shared__ int lls[16];
    const int t = threadIdx.x;
    const int lane = t & 63, w = t >> 6;
    const int rid = blockIdx.x;              // h*2048 + q
    const int h = rid >> 11, q = rid & 2047;
    const float* row = attn + (size_t)rid * NJ;

    float v0 = row[t];
    float v1 = (t < 60) ? row[256 + t] : -1e30f;
    float m = fmaxf(v0, v1);
    #pragma unroll
    for (int d = 1; d < 64; d <<= 1) m = fmaxf(m, __shfl_xor(m, d));
    if (lane == 0) red[w] = m;
    __syncthreads();
    m = fmaxf(fmaxf(red[0], red[1]), fmaxf(red[2], red[3]));

    float e0 = expf(v0 - m);
    float e1 = (t < 60) ? expf(v1 - m) : 0.f;
    float s = e0 + e1;
    #pragma unroll
    for (int d = 1; d < 64; d <<= 1) s += __shfl_xor(s, d);
    if (lane == 0) red[4 + w] = s;
    __syncthreads();
    s = (red[4] + red[5]) + (red[6] + red[7]);
    const float inv = 1.f / s;

    float sf = (t < 16) ? e0 : 0.f;
    #pragma unroll
    for (int d = 1; d < 64; d <<= 1) sf += __shfl_xor(sf, d);
    if (lane == 0) red[w] = sf;

    float a0 = e0 * inv;
    float a1 = (t < 60) ? e1 * inv : 0.f;
    awh[(size_t)rid * 320 + t] = f2bf(a0);
    if (t < 64)
        awh[(size_t)rid * 320 + 256 + t] = f2bf(a1);
    if (t < 16) {
        w16[t] = a0;
        lls[t] = lin[q * 128 + h * 16 + t];
    }
    __syncthreads();
    if (t == 0)
        s0[rid] = ((red[0] + red[1]) + (red[2] + red[3])) * inv;

    float acc = 0.f;
    #pragma unroll
    for (int k = 0; k < 16; ++k) {
        unsigned int u = inflatP[lls[k] * 256 + t];
        acc += w16[k] * (bf2f((unsigned short)(u & 0xffff)) +
                         bf2f((unsigned short)(u >> 16)));
    }
    unsigned short hh = f2bf(acc);
    KAh[(size_t)rid * 256 + t] = hh;
    KAl[(size_t)rid * 256 + t] = f2bf(acc - bf2f(hh));
}

// ---------------------------------------------------------------------------
__global__ __launch_bounds__(256) void final_kernel(
    const float* __restrict__ qf, const float* __restrict__ OH,
    const float* __restrict__ s0, const float* __restrict__ bv,
    const float* __restrict__ Wmix, float* __restrict__ out)
{
    const int q = blockIdx.x, c = threadIdx.x;
    float wj[9], m = -1e30f;
    #pragma unroll
    for (int j = 0; j < 9; ++j) { wj[j] = Wmix[c * 9 + j]; m = fmaxf(m, wj[j]); }
    float s = 0.f;
    #pragma unroll
    for (int j = 0; j < 9; ++j) { wj[j] = expf(wj[j] - m); s += wj[j]; }
    float inv = 1.f / s;
    float acc = qf[q * 256 + c] * wj[8] * inv;
    #pragma unroll
    for (int h = 0; h < 8; ++h) {
        float s0v = s0[h * 2048 + q];
        float oh = OH[((size_t)h * 2048 + q) * 256 + c]
                 + s0v * bv[(2 * h) * 256 + c]
                 + (1.f - s0v) * bv[(2 * h + 1) * 256 + c];
        acc += oh * wj[h] * inv;
    }
    out[q * 256 + c] = acc;
}

// ---------------------------------------------------------------------------
extern "C" void kernel_launch(void* const* d_in, const int* in_sizes, int n_in,
                              void* d_out, int out_size, void* d_ws, size_t ws_size,
                              hipStream_t stream) {
    const float* query = (const float*)d_in[0];
    const float* refp  = (const float*)d_in[1];
    const float* inflat= (const float*)d_in[2];
    const int*   iss   = (const int*)d_in[3];
    const float* ak    = (const float*)d_in[4];
    const int*   lsi   = (const int*)d_in[5];
    const float* Woff  = (const float*)d_in[6];
    const float* boff  = (const float*)d_in[7];
    const float* Wattn = (const float*)d_in[8];
    const float* Wv    = (const float*)d_in[9];
    const float* bv    = (const float*)d_in[10];
    const float* Wmix  = (const float*)d_in[11];
    float* out = (float*)d_out;

    typedef unsigned short us;
    char* ws = (char*)d_ws;
    int* lin    = (int*)ws;   ws += (size_t)262144 * 4;
    float* attn = (float*)ws; ws += (size_t)8 * 2048 * NJ * 4;
    float* s0   = (float*)ws; ws += (size_t)8 * 2048 * 4;
    unsigned int* inflatP = (unsigned int*)ws; ws += (size_t)1392640 * 4;
    us* qh  = (us*)ws; ws += (size_t)524288 * 2;
    us* ql  = (us*)ws; ws += (size_t)524288 * 2;
    us* akh = (us*)ws; ws += (size_t)320 * 256 * 2;
    us* akl = (us*)ws; ws += (size_t)320 * 256 * 2;
    us* Waddh = (us*)ws; ws += (size_t)524288 * 2;
    us* Waddl = (us*)ws; ws += (size_t)524288 * 2;
    us* Wvh = (us*)ws; ws += (size_t)1048576 * 2;
    us* Wvl = (us*)ws; ws += (size_t)1048576 * 2;
    us* Bhh = (us*)ws; ws += (size_t)8 * 320 * 256 * 2;
    us* Bhl = (us*)ws; ws += (size_t)8 * 320 * 256 * 2;
    us* V2Th= (us*)ws; ws += (size_t)8 * 256 * 320 * 2;   // [z][c][k], k-pad 0
    us* V2Tl= (us*)ws; ws += (size_t)8 * 256 * 320 * 2;
    us* awh = (us*)ws; ws += (size_t)8 * 2048 * 320 * 2;
    us* KAh = (us*)ws; ws += (size_t)8 * 2048 * 256 * 2;
    us* KAl = (us*)ws; ws += (size_t)8 * 2048 * 256 * 2;
    float* OH = (float*)ws;   ws += (size_t)8 * 2048 * 256 * 4;

    cvt_all_kernel<<<3491, 256, 0, stream>>>(
        query, qh, ql, ak, akh, akl, Wv, Wvh, Wvl,
        inflat, inflatP, Wattn, Waddh, Waddl, V2Th, V2Tl);
    lin_kernel<<<256, 256, 0, stream>>>(query, refp, iss, lsi, Woff, boff, lin);

    Seg sz = {nullptr, nullptr, nullptr, nullptr, 0, 0, 0, 0L, 0L, 0};

    // One dispatch, two jobs:
    //  A (bx 0-1): Bh[z] = ak @ Wadd[z]^T     (M=300, N=256, K=256, 3-prod)
    //  B (bx 2-4): V2T[z][c][16+x] = Wv1@ak^T (M=256, N=300, K=256, 2-prod)
    {
        Seg a = {akh, akl, Waddh, Waddl, 256, 256, 256, 0L, 65536L, 3};
        Seg b = {Wvh + 65536, Wvl + 65536, akh, nullptr, 256, 256, 256,
                 131072L, 0L, 2};
        mfma_gemm_dual<<<dim3(5, 5, 8), 256, 0, stream>>>(
            a, 300, 256, 256, 320L * 256, Bhh, Bhl,
            b, 256, 300, 320, 256L * 320, V2Th + 16, V2Tl + 16, 2);
    }
    // attn_a logits = qf @ Bh^T  (M=2048, N=300, K=256, 3-prod) -> attn[...,16:]
    {
        Seg a = {qh, ql, Bhh, Bhl, 256, 256, 256, 0L, 320L * 256, 3};
        mfma_gemm<false, true, 1><<<dim3(3, 32, 8), 256, 0, stream>>>(
            a, sz, attn + 16, nullptr, nullptr, 2048, 300, NJ, 2048L * NJ);
    }

    gattn_mfma<<<1024, 256, 0, stream>>>(qh, ql, inflatP, Wattn, lin, attn);

    softmax_ka_kernel<<<16384, 256, 0, stream>>>(attn, inflatP, lin, s0,
                                                 awh, KAh, KAl);

    // OH[z] = KA[z] @ Wv0[z]^T (2-prod) + aw[z] @ V2T[z]^T (1-prod, K=320)
    {
        Seg a = {KAh, KAl, Wvh, nullptr, 256, 256, 256, 2048L * 256,
                 2L * 65536, 2};
        Seg b = {awh, nullptr, V2Th, nullptr, 320, 320, 320, 2048L * 320,
                 256L * 320, 1};
        mfma_gemm<false, true, 2><<<dim3(2, 32, 8), 256, 0, stream>>>(
            a, b, OH, nullptr, nullptr, 2048, 256, 256, 2048L * 256);
    }

    final_kernel<<<2048, 256, 0, stream>>>(query, OH, s0, bv, Wmix, out);
}